// Round 11
// baseline (535.926 us; speedup 1.0000x reference)
//
#include <hip/hip_runtime.h>
#include <hip/hip_bf16.h>
#include <stdint.h>

#define N_CLAIM    100000
#define N_ENTITY   200000
#define N_EVIDENCE 150000
#define NEDGE      2000000
#define F          64
#define NT         550000      // concat dst: t0 claim [0,100K) t1 claim [100K,200K) t2 ent [200K,400K) t3 evid [400K,550K)
#define BATCH      50000

#define BSH   10
#define NBKT  538
#define CAP   24576
#define B3_BLOCKS 2000
#define B3_BPT    500          // blocks per edge type (uniform type per block)
#define B3_CHUNK  4000         // 500*4000 = 2,000,000 edges per type
#define NBITS_W   3136         // ceil(100000/32) words for claim bitmask
#define NEB       (N_ENTITY/64)            // 3125 entity blocks
#define NVB       ((N_EVIDENCE+63)/64)     // 2344 evidence blocks
#define NCB       ((BATCH+63)/64)          // 782 claim blocks (cap; runtime M=*nu)

#define NC4 (N_CLAIM * F / 4)
#define NE4 (N_ENTITY * F / 4)
#define NV4 (N_EVIDENCE * F / 4)
#define NTOT4 (NC4 + NE4 + NV4)
#define CASTB 6144
#define RANKB ((N_CLAIM + 255) / 256)      // 391
#define FRONTB (B3_BLOCKS + CASTB + RANKB) // 8535
#define L1B    (NCB + NEB + NVB)

// LDS tile: 64 rows x 64 shorts, 8 x 16B chunks per row, XOR swizzle (chunk ^ row&7).
#define SWZ(row, chunk) (((row) << 6) + ((((chunk) ^ ((row) & 7))) << 3))

static __device__ __forceinline__ float b2f(unsigned short u){
  return __uint_as_float(((unsigned int)u) << 16);
}
static __device__ __forceinline__ unsigned short f2b(float f){
  unsigned int x = __float_as_uint(f);
  x += 0x7fffu + ((x >> 16) & 1u);   // RNE
  return (unsigned short)(x >> 16);
}

typedef float f32x2v __attribute__((ext_vector_type(2)));

static __device__ __forceinline__ f32x2v pk_add(f32x2v a, f32x2v b){
  f32x2v d;
  asm("v_pk_add_f32 %0, %1, %2" : "=v"(d) : "v"(a), "v"(b));
  return d;
}
static __device__ __forceinline__ f32x2v unp(unsigned int w){
  f32x2v r;
  r.x = __uint_as_float(w << 16);
  r.y = __uint_as_float(w & 0xffff0000u);
  return r;
}

typedef __bf16 bf16x8 __attribute__((ext_vector_type(8)));
typedef float  f32x4  __attribute__((ext_vector_type(4)));

// ---------------- mark used claims + init bucket cursors ----------------
__global__ void k_mark(const int* __restrict__ cbi, unsigned int* __restrict__ bits,
                       int* __restrict__ cursor){
  int i = blockIdx.x * blockDim.x + threadIdx.x;
  if (i < NBKT) cursor[i] = i * CAP;
  if (i < BATCH){
    int c = cbi[i];
    atomicOr(&bits[c >> 5], 1u << (c & 31));
  }
}

// ---------------- front mega-kernel: bscatter | cast3 | rank, TYPE-STRIPED ----------------
// bids [0,8000): bid%4==0 -> bscatter (bid>>2), else cast (3*(bid>>2)+(bid&3)-1)
// bids [8000,8144): cast 6000+...   bids [8144,8535): rank
__global__ __launch_bounds__(256) void k_front(const int* __restrict__ ei,
                                               const unsigned int* __restrict__ bits,
                                               int* __restrict__ cursor,
                                               unsigned int* __restrict__ pairs,
                                               const float* __restrict__ xc,
                                               const float* __restrict__ xe,
                                               const float* __restrict__ xv,
                                               unsigned short* __restrict__ oc,
                                               unsigned short* __restrict__ oe,
                                               unsigned short* __restrict__ ov,
                                               int* __restrict__ rank,
                                               int* __restrict__ list,
                                               int* __restrict__ nu){
  __shared__ int hl[2 * NBKT];
  int tid = threadIdx.x;
  int bid = blockIdx.x;
  int wt, wi;
  if (bid < 8000){
    int g = bid >> 2, r = bid & 3;
    if (r == 0){ wt = 0; wi = g; }
    else       { wt = 1; wi = g * 3 + (r - 1); }
  } else if (bid < 8000 + 144){ wt = 1; wi = 6000 + (bid - 8000); }
  else { wt = 2; wi = bid - 8144; }

  if (wt == 0){
    // ---- bucket scatter: int4 loads, single-atomic rank capture ----
    int* hcnt = hl;
    int* hpos = hl + NBKT;
    const int toff[4] = {0, N_CLAIM, 2*N_CLAIM, 2*N_CLAIM + N_ENTITY};
    int bpt = wi / B3_BPT;
    int e0  = (wi - bpt * B3_BPT) * B3_CHUNK;
    int off_t = toff[bpt];
    bool isclaim = (bpt < 2);
    const int* dstp = ei + (size_t)bpt * 2 * NEDGE + NEDGE + e0;
    const int* srcp = ei + (size_t)bpt * 2 * NEDGE + e0;
    for (int b = tid; b < NBKT; b += 256) hcnt[b] = 0;
    __syncthreads();
    unsigned int v[16];
    int4 dv[4];
    #pragma unroll
    for (int i = 0; i < 4; ++i){
      int base = (i * 256 + tid) * 4;
      dv[i] = make_int4(0, 0, 0, 0);
      if (base < B3_CHUNK) dv[i] = *(const int4*)(dstp + base);   // groups are all-in or all-out (4000%4==0)
    }
    #pragma unroll
    for (int i = 0; i < 4; ++i){
      int base = (i * 256 + tid) * 4;
      #pragma unroll
      for (int k = 0; k < 4; ++k){
        unsigned int vv = 0xFFFFFFFFu;
        if (base < B3_CHUNK){
          int dst = (&dv[i].x)[k];
          if (!isclaim || ((bits[dst >> 5] >> (dst & 31)) & 1u))
            vv = (unsigned int)(dst + off_t);
        }
        v[i * 4 + k] = vv;
      }
    }
    int r16[16];
    #pragma unroll
    for (int j = 0; j < 16; ++j){
      r16[j] = 0;
      if (v[j] != 0xFFFFFFFFu) r16[j] = atomicAdd(&hcnt[v[j] >> BSH], 1);  // rank within block
    }
    __syncthreads();
    for (int b = tid; b < NBKT; b += 256){
      int c = hcnt[b];
      hpos[b] = c ? atomicAdd(&cursor[b], c) : 0;
    }
    __syncthreads();
    int4 sv[4];
    #pragma unroll
    for (int i = 0; i < 4; ++i){
      int base = (i * 256 + tid) * 4;
      sv[i] = make_int4(0, 0, 0, 0);
      if (base < B3_CHUNK) sv[i] = *(const int4*)(srcp + base);
    }
    #pragma unroll
    for (int i = 0; i < 4; ++i){
      #pragma unroll
      for (int k = 0; k < 4; ++k){
        int j = i * 4 + k;
        if (v[j] != 0xFFFFFFFFu){
          int o = hpos[v[j] >> BSH] + r16[j];                      // no atomic here
          pairs[o] = ((v[j] & ((1u << BSH) - 1)) << 18) | (unsigned int)(&sv[i].x)[k];
        }
      }
    }
  } else if (wt == 1){
    // ---- fp32 -> bf16 cast, grid-strided over all three tables ----
    for (int i = wi * 256 + tid; i < NTOT4; i += CASTB * 256){
      const float* in; unsigned short* out; int j;
      if (i < NC4){ in = xc; out = oc; j = i; }
      else if (i < NC4 + NE4){ in = xe; out = oe; j = i - NC4; }
      else { in = xv; out = ov; j = i - NC4 - NE4; }
      float4 fv = ((const float4*)in)[j];
      ushort4 o;
      o.x = f2b(fv.x); o.y = f2b(fv.y); o.z = f2b(fv.z); o.w = f2b(fv.w);
      ((ushort4*)out)[j] = o;
    }
  } else {
    // ---- rank/compact used claims ----
    int i = wi * 256 + tid;
    if (i < N_CLAIM && ((bits[i >> 5] >> (i & 31)) & 1u)){
      int r = atomicAdd(nu, 1);
      rank[i] = r;
      list[r] = i;
    }
  }
}

// ---------------- CSR finalize: per-block self-scan of bucket counts ----------------
__global__ __launch_bounds__(1024) void k_csr(const unsigned int* __restrict__ pairs,
                                              const int* __restrict__ cursor,
                                              int* __restrict__ R, int* __restrict__ col){
  __shared__ int h[1024];
  __shared__ int s[1024];
  int b = blockIdx.x, tid = threadIdx.x;
  int cb = (tid < NBKT) ? (cursor[tid] - tid * CAP) : 0;
  s[tid] = cb;
  __syncthreads();
  for (int off = 1; off < 1024; off <<= 1){
    int t = (tid >= off) ? s[tid - off] : 0;
    __syncthreads();
    s[tid] += t;
    __syncthreads();
  }
  int cnt  = cursor[b] - b * CAP;
  int base = s[b] - cnt;
  if (b == 0 && tid == 1023) R[NT] = s[1023];
  __syncthreads();
  int pbase = b * CAP;
  h[tid] = 0;
  __syncthreads();
  for (int i = tid; i < cnt; i += 1024)
    atomicAdd(&h[pairs[pbase + i] >> 18], 1);
  __syncthreads();
  int c = h[tid];
  s[tid] = c;
  __syncthreads();
  for (int off = 1; off < 1024; off <<= 1){
    int t = (tid >= off) ? s[tid - off] : 0;
    __syncthreads();
    s[tid] += t;
    __syncthreads();
  }
  int ex = s[tid] - c;
  h[tid] = ex;
  int n = (b << BSH) + tid;
  if (n < NT) R[n] = base + ex;
  __syncthreads();
  for (int i = tid; i < cnt; i += 1024){
    unsigned int p = pairs[pbase + i];
    int r = atomicAdd(&h[p >> 18], 1);
    col[base + r] = (int)(p & 0x3FFFFu);
  }
}

// ---- shared helpers for the fused agg+GEMM kernels ----
static __device__ __forceinline__ void stage_w(const float* __restrict__ W,
                                               unsigned short* __restrict__ T,
                                               int n, int oct){
  unsigned int pk[4];
  #pragma unroll
  for (int i = 0; i < 4; i++){
    float lo = W[(oct * 8 + 2 * i)     * 64 + n];
    float hi = W[(oct * 8 + 2 * i + 1) * 64 + n];
    pk[i] = ((unsigned int)f2b(hi) << 16) | f2b(lo);
  }
  *(uint4*)(T + SWZ(n, oct)) = *(uint4*)pk;
}

static __device__ __forceinline__ void gather_mean(
    const unsigned short* __restrict__ X, const int* __restrict__ col,
    int rbeg, int rend, int g, int fl, f32x2v acc[4]){
  int cid = 0;
  int deg = rend - rbeg;
  if (fl < deg) cid = col[rbeg + fl];
  for (int p = rbeg; p < rend; p += 8){
    int nb = rend - p; if (nb > 8) nb = 8;
    int cc = cid;
    int rem = rend - (p + 8);
    if (rem > 0 && fl < rem) cid = col[p + 8 + fl];
    #pragma unroll
    for (int k = 0; k < 8; ++k){
      int c = __shfl(cc, (g << 3) + k, 64);
      if (k < nb){
        uint4 d = *(const uint4*)(X + (long long)c * F + fl * 8);
        acc[0] = pk_add(acc[0], unp(d.x));
        acc[1] = pk_add(acc[1], unp(d.y));
        acc[2] = pk_add(acc[2], unp(d.z));
        acc[3] = pk_add(acc[3], unp(d.w));
      }
    }
  }
}

static __device__ __forceinline__ uint4 mean_pack(f32x2v acc[4], int deg){
  float r = deg ? (1.0f / (float)deg) : 0.f;
  uint4 o;
  o.x = ((unsigned int)f2b(acc[0].y * r) << 16) | f2b(acc[0].x * r);
  o.y = ((unsigned int)f2b(acc[1].y * r) << 16) | f2b(acc[1].x * r);
  o.z = ((unsigned int)f2b(acc[2].y * r) << 16) | f2b(acc[2].x * r);
  o.w = ((unsigned int)f2b(acc[3].y * r) << 16) | f2b(acc[3].x * r);
  return o;
}

// ---- entity/evidence fused agg+GEMM body (uses first 3*4096 shorts of L = 24 KB) ----
static __device__ __forceinline__ void aggemm_body(int b, unsigned short* L,
    const unsigned short* __restrict__ Xg,
    const unsigned short* __restrict__ Xe, const unsigned short* __restrict__ Xv,
    const int* __restrict__ R, const int* __restrict__ col,
    const float* __restrict__ Wl, const float* __restrict__ Wr,
    const float* __restrict__ bl,
    unsigned short* __restrict__ He, unsigned short* __restrict__ Hv)
{
  unsigned short* WTm = L;
  unsigned short* WTr = L + 4096;
  unsigned short* MT  = L + 2 * 4096;
  int seg, m0, Rb, Ms;
  const unsigned short* Xroot;
  unsigned short* Hout;
  if (b < NEB){ seg = 0; m0 = b * 64;         Rb = 2*N_CLAIM;            Ms = N_ENTITY;   Xroot = Xe; Hout = He; }
  else        { seg = 1; m0 = (b - NEB) * 64; Rb = 2*N_CLAIM + N_ENTITY; Ms = N_EVIDENCE; Xroot = Xv; Hout = Hv; }
  int tid = threadIdx.x;
  int sn = tid & 63, soct = tid >> 6;
  stage_w(Wl + (size_t)(2 + seg) * 4096, WTm, sn, soct);
  stage_w(Wr + (size_t)(2 + seg) * 4096, WTr, sn, soct);
  int lane = tid & 63;
  int wv   = tid >> 6;
  int g    = lane >> 3;
  int fl   = lane & 7;
  int rowl = wv * 8 + g;
  int rowg = m0 + rowl;
  bool act = rowg < Ms;
  int rbeg = 0, rend = 0;
  if (act){ rbeg = R[Rb + rowg]; rend = R[Rb + rowg + 1]; }
  f32x2v z = {0.f, 0.f};
  f32x2v acc[4] = {z, z, z, z};
  gather_mean(Xg, col, rbeg, rend, g, fl, acc);
  *(uint4*)(MT + SWZ(rowl, fl)) = mean_pack(acc, rend - rbeg);
  __syncthreads();
  int rt = wv >> 1;
  int c0 = (wv & 1) * 2;
  int quad = lane >> 4, l16 = lane & 15;
  int arow = m0 + rt * 16 + l16; if (arow >= Ms) arow = Ms - 1;
  f32x4 zz = {0.f, 0.f, 0.f, 0.f};
  f32x4 gacc[2] = {zz, zz};
  #pragma unroll
  for (int kk = 0; kk < 64; kk += 32){
    int ch = (kk >> 3) + quad;
    bf16x8 am = *(const bf16x8*)(MT + SWZ(rt * 16 + l16, ch));
    bf16x8 ar = *(const bf16x8*)(Xroot + (long long)arow * F + kk + quad * 8);
    #pragma unroll
    for (int c = 0; c < 2; c++){
      int bn = (c0 + c) * 16 + l16;
      bf16x8 bm = *(const bf16x8*)(WTm + SWZ(bn, ch));
      bf16x8 br = *(const bf16x8*)(WTr + SWZ(bn, ch));
      gacc[c] = __builtin_amdgcn_mfma_f32_16x16x32_bf16(am, bm, gacc[c], 0, 0, 0);
      gacc[c] = __builtin_amdgcn_mfma_f32_16x16x32_bf16(ar, br, gacc[c], 0, 0, 0);
    }
  }
  const float* blp = bl + (size_t)(2 + seg) * 64;
  #pragma unroll
  for (int c = 0; c < 2; c++){
    int n = (c0 + c) * 16 + l16;
    float bv = blp[n];
    #pragma unroll
    for (int r4 = 0; r4 < 4; r4++){
      int row = m0 + rt * 16 + quad * 4 + r4;
      if (row < Ms){
        float v2 = gacc[c][r4] + bv;
        Hout[(long long)row * F + n] = f2b(fmaxf(v2, 0.f));
      }
    }
  }
}

// ---- claims fused agg+GEMM body: 4 weight tiles + ONE mean tile (40 KB) ----
static __device__ __forceinline__ void cagg_body(int bid, unsigned short* L,
    const unsigned short* __restrict__ Xg0, const unsigned short* __restrict__ Xg1,
    const unsigned short* __restrict__ Xr,
    const int* __restrict__ R, const int* __restrict__ col,
    const int* __restrict__ list, const int* __restrict__ nu_ptr,
    const float* __restrict__ W0, const float* __restrict__ W1,
    const float* __restrict__ W2, const float* __restrict__ W3,
    const float* __restrict__ b0, const float* __restrict__ b1,
    unsigned short* __restrict__ Hout, int rootlist, int relu,
    const float* __restrict__ Wc, float* __restrict__ logits)
{
  int M = *nu_ptr;
  if (bid * 64 >= M) return;
  unsigned short* WT = L;               // 4 x 8 KB weight tiles
  unsigned short* MT = L + 4 * 4096;    // 8 KB mean tile (reused seg0 -> seg1)
  int tid = threadIdx.x;
  int sn = tid & 63, soct = tid >> 6;
  stage_w(W0, WT,            sn, soct);
  stage_w(W1, WT + 4096,     sn, soct);
  stage_w(W2, WT + 2 * 4096, sn, soct);
  stage_w(W3, WT + 3 * 4096, sn, soct);
  int m0 = bid * 64;
  int lane = tid & 63;
  int wv   = tid >> 6;
  int g    = lane >> 3;
  int fl   = lane & 7;
  int rowl = wv * 8 + g;
  int rowg = m0 + rowl;
  bool act = rowg < M;
  int node0 = act ? list[rowg] : 0;
  // ---- seg0 gather ----
  {
    int rbeg = 0, rend = 0;
    if (act){ rbeg = R[node0]; rend = R[node0 + 1]; }
    f32x2v z = {0.f, 0.f};
    f32x2v acc[4] = {z, z, z, z};
    gather_mean(Xg0, col, rbeg, rend, g, fl, acc);
    *(uint4*)(MT + SWZ(rowl, fl)) = mean_pack(acc, rend - rbeg);
  }
  __syncthreads();
  // ---- GEMM pass A: mean0@W0 + root@W2 + root@W3 ----
  int rt = wv >> 1;
  int c0 = (wv & 1) * 2;
  int quad = lane >> 4, l16 = lane & 15;
  int arow = m0 + rt * 16 + l16; if (arow >= M) arow = M - 1;
  long long rrow = rootlist ? list[arow] : arow;
  f32x4 zz = {0.f, 0.f, 0.f, 0.f};
  f32x4 gacc[2] = {zz, zz};
  #pragma unroll
  for (int kk = 0; kk < 64; kk += 32){
    int ch = (kk >> 3) + quad;
    bf16x8 a0 = *(const bf16x8*)(MT + SWZ(rt * 16 + l16, ch));
    bf16x8 ar = *(const bf16x8*)(Xr + rrow * F + kk + quad * 8);
    #pragma unroll
    for (int c = 0; c < 2; c++){
      int bn = (c0 + c) * 16 + l16;
      bf16x8 w0 = *(const bf16x8*)(WT +            SWZ(bn, ch));
      bf16x8 w2 = *(const bf16x8*)(WT + 2 * 4096 + SWZ(bn, ch));
      bf16x8 w3 = *(const bf16x8*)(WT + 3 * 4096 + SWZ(bn, ch));
      gacc[c] = __builtin_amdgcn_mfma_f32_16x16x32_bf16(a0, w0, gacc[c], 0, 0, 0);
      gacc[c] = __builtin_amdgcn_mfma_f32_16x16x32_bf16(ar, w2, gacc[c], 0, 0, 0);
      gacc[c] = __builtin_amdgcn_mfma_f32_16x16x32_bf16(ar, w3, gacc[c], 0, 0, 0);
    }
  }
  __syncthreads();   // all waves done reading MT (seg0)
  // ---- seg1 gather (overwrites MT) ----
  {
    int n1 = node0 + N_CLAIM;
    int rbeg = 0, rend = 0;
    if (act){ rbeg = R[n1]; rend = R[n1 + 1]; }
    f32x2v z = {0.f, 0.f};
    f32x2v acc[4] = {z, z, z, z};
    gather_mean(Xg1, col, rbeg, rend, g, fl, acc);
    *(uint4*)(MT + SWZ(rowl, fl)) = mean_pack(acc, rend - rbeg);
  }
  __syncthreads();
  // ---- GEMM pass B: mean1@W1 ----
  #pragma unroll
  for (int kk = 0; kk < 64; kk += 32){
    int ch = (kk >> 3) + quad;
    bf16x8 a1 = *(const bf16x8*)(MT + SWZ(rt * 16 + l16, ch));
    #pragma unroll
    for (int c = 0; c < 2; c++){
      int bn = (c0 + c) * 16 + l16;
      bf16x8 w1 = *(const bf16x8*)(WT + 4096 + SWZ(bn, ch));
      gacc[c] = __builtin_amdgcn_mfma_f32_16x16x32_bf16(a1, w1, gacc[c], 0, 0, 0);
    }
  }
  if (!logits){
    // ---- store hidden (layer 1) ----
    #pragma unroll
    for (int c = 0; c < 2; c++){
      int n = (c0 + c) * 16 + l16;
      float bv = b0[n] + b1[n];
      #pragma unroll
      for (int r4 = 0; r4 < 4; r4++){
        int row = m0 + rt * 16 + quad * 4 + r4;
        if (row < M){
          float v2 = gacc[c][r4] + bv;
          if (relu) v2 = fmaxf(v2, 0.f);
          Hout[(long long)row * F + n] = f2b(v2);
        }
      }
    }
  } else {
    // ---- fused classifier: logits[row] = (h2row) @ Wc (bias bc added in k_out2) ----
    __syncthreads();                    // done reading MT; reuse as partial buffer
    float* P = (float*)MT;              // P[row64][half][j] : 64*2*2 floats = 1 KB
    #pragma unroll
    for (int r4 = 0; r4 < 4; r4++){
      float p0 = 0.f, p1 = 0.f;
      #pragma unroll
      for (int c = 0; c < 2; c++){
        int n = (c0 + c) * 16 + l16;
        float v2 = gacc[c][r4] + b0[n] + b1[n];
        p0 += v2 * Wc[n * 2];
        p1 += v2 * Wc[n * 2 + 1];
      }
      #pragma unroll
      for (int off = 8; off; off >>= 1){
        p0 += __shfl_xor(p0, off, 64);
        p1 += __shfl_xor(p1, off, 64);
      }
      if (l16 == 0){
        int row = rt * 16 + quad * 4 + r4;
        P[row * 4 + (wv & 1) * 2]     = p0;
        P[row * 4 + (wv & 1) * 2 + 1] = p1;
      }
    }
    __syncthreads();
    if (tid < 128){
      int row = tid >> 1, j = tid & 1;
      if (m0 + row < M)
        logits[(long long)(m0 + row) * 2 + j] = P[row * 4 + j] + P[row * 4 + 2 + j];
    }
  }
}

// ---------------- layer-1 mega-kernel: claims cagg | ent/evid aggemm ----------------
__global__ __launch_bounds__(512) void k_l1(
    const int* __restrict__ R, const int* __restrict__ col,
    const unsigned short* __restrict__ xb_c, const unsigned short* __restrict__ xb_e,
    const unsigned short* __restrict__ xb_v,
    const int* __restrict__ list, const int* __restrict__ nu,
    const float* __restrict__ Wl1, const float* __restrict__ Wr1,
    const float* __restrict__ bl1,
    unsigned short* __restrict__ h1c, unsigned short* __restrict__ h1e,
    unsigned short* __restrict__ h1v)
{
  __shared__ __align__(16) unsigned short L[5 * 4096];   // 40 KB -> 4 blocks/CU
  int bid = blockIdx.x;
  if (bid < NCB){
    cagg_body(bid, L, xb_e, xb_v, xb_c, R, col, list, nu,
              Wl1, Wl1 + 4096, Wr1, Wr1 + 4096, bl1, bl1 + 64, h1c, 1, 1,
              nullptr, nullptr);
  } else {
    aggemm_body(bid - NCB, L, xb_c, xb_e, xb_v, R, col, Wl1, Wr1, bl1, h1e, h1v);
  }
}

// ---------------- layer-2 claims kernel + fused classifier ----------------
__global__ __launch_bounds__(512) void k_cagg2(
    const unsigned short* __restrict__ h1e, const unsigned short* __restrict__ h1v,
    const unsigned short* __restrict__ h1c,
    const int* __restrict__ R, const int* __restrict__ col,
    const int* __restrict__ list, const int* __restrict__ nu,
    const float* __restrict__ Wl2, const float* __restrict__ Wr2,
    const float* __restrict__ bl2,
    const float* __restrict__ Wc, float* __restrict__ logits)
{
  __shared__ __align__(16) unsigned short L[5 * 4096];   // 40 KB
  cagg_body(blockIdx.x, L, h1e, h1v, h1c, R, col, list, nu,
            Wl2, Wl2 + 4096, Wr2, Wr2 + 4096, bl2, bl2 + 64, nullptr, 0, 0,
            Wc, logits);
}

// ---------------- final: per-batch logit gather + bias ----------------
__global__ void k_out2(const float* __restrict__ logits,
                       const int* __restrict__ cbi,
                       const int* __restrict__ rank,
                       const float* __restrict__ bcp,
                       float* __restrict__ out){
  int w = blockIdx.x * blockDim.x + threadIdx.x;
  if (w >= BATCH) return;
  int rk = rank[cbi[w]];
  float2 l = ((const float2*)logits)[rk];
  out[2 * w]     = l.x + bcp[0];
  out[2 * w + 1] = l.y + bcp[1];
}

extern "C" void kernel_launch(void* const* d_in, const int* in_sizes, int n_in,
                              void* d_out, int out_size, void* d_ws, size_t ws_size,
                              hipStream_t stream)
{
  const float* x_c = (const float*)d_in[0];
  const float* x_e = (const float*)d_in[1];
  const float* x_v = (const float*)d_in[2];
  const int*   ei  = (const int*)d_in[3];
  const int*   cbi = (const int*)d_in[4];
  const float* Wl1 = (const float*)d_in[5];
  const float* bl1 = (const float*)d_in[6];
  const float* Wr1 = (const float*)d_in[7];
  const float* Wl2 = (const float*)d_in[8];
  const float* bl2 = (const float*)d_in[9];
  const float* Wr2 = (const float*)d_in[10];
  const float* Wc  = (const float*)d_in[11];
  const float* bc  = (const float*)d_in[12];
  float* out = (float*)d_out;

  char* ws = (char*)d_ws;
  size_t off = 0;
  auto alloc = [&](size_t bytes) -> char* {
    char* p = ws + off;
    off += (bytes + 255) & ~(size_t)255;
    return p;
  };
  int* R       = (int*)alloc((size_t)(NT + 1) * 4);
  int* cursor  = (int*)alloc((size_t)NBKT * 4);
  unsigned int* bits = (unsigned int*)alloc((size_t)NBITS_W * 4);
  int* rank    = (int*)alloc((size_t)N_CLAIM * 4);
  int* list    = (int*)alloc((size_t)BATCH * 4);
  int* nu      = (int*)alloc(256);
  int* col     = (int*)alloc((size_t)4 * NEDGE * 4);
  unsigned int* pairs = (unsigned int*)alloc((size_t)NBKT * CAP * 4);   // dead after k_csr
  unsigned short* xb_c  = (unsigned short*)alloc((size_t)N_CLAIM    * F * 2);
  unsigned short* xb_e  = (unsigned short*)alloc((size_t)N_ENTITY   * F * 2);
  unsigned short* xb_v  = (unsigned short*)alloc((size_t)N_EVIDENCE * F * 2);
  unsigned short* h1c   = (unsigned short*)alloc((size_t)BATCH * F * 2);   // compacted
  unsigned short* h1e   = (unsigned short*)alloc((size_t)N_ENTITY   * F * 2);
  unsigned short* h1v   = (unsigned short*)alloc((size_t)N_EVIDENCE * F * 2);
  float* logits = (float*)pairs;   // alias dead pairs region; [BATCH][2] fp32

  hipMemsetAsync(bits, 0, (size_t)NBITS_W * 4, stream);
  hipMemsetAsync(nu, 0, 4, stream);

  k_mark<<<(BATCH + 255) / 256, 256, 0, stream>>>(cbi, bits, cursor);

  k_front<<<FRONTB, 256, 0, stream>>>(ei, bits, cursor, pairs,
      x_c, x_e, x_v, xb_c, xb_e, xb_v, rank, list, nu);

  k_csr<<<NBKT, 1024, 0, stream>>>(pairs, cursor, R, col);

  k_l1<<<L1B, 512, 0, stream>>>(R, col, xb_c, xb_e, xb_v, list, nu,
      Wl1, Wr1, bl1, h1c, h1e, h1v);

  k_cagg2<<<NCB, 512, 0, stream>>>(h1e, h1v, h1c, R, col, list, nu,
      Wl2, Wr2, bl2, Wc, logits);

  k_out2<<<(BATCH + 255) / 256, 256, 0, stream>>>(logits, cbi, rank, bc, out);
}

// Round 12
// 465.777 us; speedup vs baseline: 1.1506x; 1.1506x over previous
//
#include <hip/hip_runtime.h>
#include <hip/hip_bf16.h>
#include <stdint.h>

#define N_CLAIM    100000
#define N_ENTITY   200000
#define N_EVIDENCE 150000
#define NEDGE      2000000
#define F          64
#define NT         550000      // concat dst: t0 claim [0,100K) t1 claim [100K,200K) t2 ent [200K,400K) t3 evid [400K,550K)
#define BATCH      50000

#define BSH   10
#define NBKT  538
#define CAP   24576
#define B3_BLOCKS 2000
#define B3_BPT    500          // blocks per edge type (uniform type per block)
#define B3_CHUNK  4000         // 500*4000 = 2,000,000 edges per type
#define B3_ITER   16           // 16*256 = 4096 >= 4000 (iter 15 partial)
#define NBITS_W   3136         // ceil(100000/32) words for claim bitmask
#define NEB       (N_ENTITY/64)            // 3125 entity blocks
#define NVB       ((N_EVIDENCE+63)/64)     // 2344 evidence blocks
#define NCB       ((BATCH+63)/64)          // 782 claim blocks (cap; runtime M=*nu)

#define NC4 (N_CLAIM * F / 4)
#define NE4 (N_ENTITY * F / 4)
#define NV4 (N_EVIDENCE * F / 4)
#define NTOT4 (NC4 + NE4 + NV4)
#define CASTB 6144
#define RANKB ((N_CLAIM + 255) / 256)      // 391
#define FRONTB (CASTB + B3_BLOCKS + RANKB) // 8535; cast FIRST so bscatter enters as cast retires
#define L1B    (NCB + NEB + NVB)

// LDS tile: 64 rows x 64 shorts, 8 x 16B chunks per row, XOR swizzle (chunk ^ row&7).
#define SWZ(row, chunk) (((row) << 6) + ((((chunk) ^ ((row) & 7))) << 3))

static __device__ __forceinline__ float b2f(unsigned short u){
  return __uint_as_float(((unsigned int)u) << 16);
}
static __device__ __forceinline__ unsigned short f2b(float f){
  unsigned int x = __float_as_uint(f);
  x += 0x7fffu + ((x >> 16) & 1u);   // RNE
  return (unsigned short)(x >> 16);
}

typedef float f32x2v __attribute__((ext_vector_type(2)));

static __device__ __forceinline__ f32x2v pk_add(f32x2v a, f32x2v b){
  f32x2v d;
  asm("v_pk_add_f32 %0, %1, %2" : "=v"(d) : "v"(a), "v"(b));
  return d;
}
static __device__ __forceinline__ f32x2v unp(unsigned int w){
  f32x2v r;
  r.x = __uint_as_float(w << 16);
  r.y = __uint_as_float(w & 0xffff0000u);
  return r;
}

typedef __bf16 bf16x8 __attribute__((ext_vector_type(8)));
typedef float  f32x4  __attribute__((ext_vector_type(4)));

// ---------------- mark used claims + init bucket cursors ----------------
__global__ void k_mark(const int* __restrict__ cbi, unsigned int* __restrict__ bits,
                       int* __restrict__ cursor){
  int i = blockIdx.x * blockDim.x + threadIdx.x;
  if (i < NBKT) cursor[i] = i * CAP;
  if (i < BATCH){
    int c = cbi[i];
    atomicOr(&bits[c >> 5], 1u << (c & 31));
  }
}

// ---------------- front mega-kernel: cast3 | bscatter | rank ----------------
// Cast blocks first: they are short and retire continuously, so the 2000
// long-running bscatter blocks become resident ~15us in and the remaining
// BW-bound cast work drains alongside bscatter's latency stalls.
__global__ __launch_bounds__(256) void k_front(const int* __restrict__ ei,
                                               const unsigned int* __restrict__ bits,
                                               int* __restrict__ cursor,
                                               unsigned int* __restrict__ pairs,
                                               const float* __restrict__ xc,
                                               const float* __restrict__ xe,
                                               const float* __restrict__ xv,
                                               unsigned short* __restrict__ oc,
                                               unsigned short* __restrict__ oe,
                                               unsigned short* __restrict__ ov,
                                               int* __restrict__ rank,
                                               int* __restrict__ list,
                                               int* __restrict__ nu){
  __shared__ int hl[2 * NBKT];
  int tid = threadIdx.x;
  int bid = blockIdx.x;
  if (bid < CASTB){
    // ---- fp32 -> bf16 cast, grid-strided over all three tables ----
    for (int i = bid * 256 + tid; i < NTOT4; i += CASTB * 256){
      const float* in; unsigned short* out; int j;
      if (i < NC4){ in = xc; out = oc; j = i; }
      else if (i < NC4 + NE4){ in = xe; out = oe; j = i - NC4; }
      else { in = xv; out = ov; j = i - NC4 - NE4; }
      float4 v = ((const float4*)in)[j];
      ushort4 o;
      o.x = f2b(v.x); o.y = f2b(v.y); o.z = f2b(v.z); o.w = f2b(v.w);
      ((ushort4*)out)[j] = o;
    }
  } else if (bid < CASTB + B3_BLOCKS){
    // ---- phase-separated register-resident bucket scatter ----
    int wb = bid - CASTB;
    int* hcnt = hl;
    int* hpos = hl + NBKT;
    const int toff[4] = {0, N_CLAIM, 2*N_CLAIM, 2*N_CLAIM + N_ENTITY};
    int bpt = wb / B3_BPT;
    int e0  = (wb - bpt * B3_BPT) * B3_CHUNK;
    int off_t = toff[bpt];
    bool isclaim = (bpt < 2);
    const int* dstp = ei + (size_t)bpt * 2 * NEDGE + NEDGE + e0;
    const int* srcp = ei + (size_t)bpt * 2 * NEDGE + e0;
    for (int b = tid; b < NBKT; b += 256) hcnt[b] = 0;
    __syncthreads();
    unsigned int v[B3_ITER];
    #pragma unroll
    for (int i = 0; i < B3_ITER; ++i){
      int li = i * 256 + tid;
      v[i] = 0xFFFFFFFFu;
      if (li < B3_CHUNK){
        int dst = dstp[li];
        if (!isclaim || ((bits[dst >> 5] >> (dst & 31)) & 1u))
          v[i] = (unsigned int)(dst + off_t);
      }
    }
    #pragma unroll
    for (int i = 0; i < B3_ITER; ++i)
      if (v[i] != 0xFFFFFFFFu) atomicAdd(&hcnt[v[i] >> BSH], 1);
    __syncthreads();
    for (int b = tid; b < NBKT; b += 256){
      int c = hcnt[b];
      hpos[b] = c ? atomicAdd(&cursor[b], c) : 0;
    }
    __syncthreads();
    int s[B3_ITER];
    #pragma unroll
    for (int i = 0; i < B3_ITER; ++i){
      int li = i * 256 + tid;
      s[i] = (li < B3_CHUNK) ? srcp[li] : 0;
    }
    #pragma unroll
    for (int i = 0; i < B3_ITER; ++i){
      if (v[i] != 0xFFFFFFFFu){
        int o = atomicAdd(&hpos[v[i] >> BSH], 1);
        pairs[o] = ((v[i] & ((1u << BSH) - 1)) << 18) | (unsigned int)s[i];
      }
    }
  } else {
    // ---- rank/compact used claims ----
    int i = (bid - CASTB - B3_BLOCKS) * 256 + tid;
    if (i < N_CLAIM && ((bits[i >> 5] >> (i & 31)) & 1u)){
      int r = atomicAdd(nu, 1);
      rank[i] = r;
      list[r] = i;
    }
  }
}

// ---------------- CSR finalize: per-block self-scan of bucket counts ----------------
__global__ __launch_bounds__(1024) void k_csr(const unsigned int* __restrict__ pairs,
                                              const int* __restrict__ cursor,
                                              int* __restrict__ R, int* __restrict__ col){
  __shared__ int h[1024];
  __shared__ int s[1024];
  int b = blockIdx.x, tid = threadIdx.x;
  int cb = (tid < NBKT) ? (cursor[tid] - tid * CAP) : 0;
  s[tid] = cb;
  __syncthreads();
  for (int off = 1; off < 1024; off <<= 1){
    int t = (tid >= off) ? s[tid - off] : 0;
    __syncthreads();
    s[tid] += t;
    __syncthreads();
  }
  int cnt  = cursor[b] - b * CAP;
  int base = s[b] - cnt;
  if (b == 0 && tid == 1023) R[NT] = s[1023];
  __syncthreads();
  int pbase = b * CAP;
  h[tid] = 0;
  __syncthreads();
  for (int i = tid; i < cnt; i += 1024)
    atomicAdd(&h[pairs[pbase + i] >> 18], 1);
  __syncthreads();
  int c = h[tid];
  s[tid] = c;
  __syncthreads();
  for (int off = 1; off < 1024; off <<= 1){
    int t = (tid >= off) ? s[tid - off] : 0;
    __syncthreads();
    s[tid] += t;
    __syncthreads();
  }
  int ex = s[tid] - c;
  h[tid] = ex;
  int n = (b << BSH) + tid;
  if (n < NT) R[n] = base + ex;
  __syncthreads();
  for (int i = tid; i < cnt; i += 1024){
    unsigned int p = pairs[pbase + i];
    int r = atomicAdd(&h[p >> 18], 1);
    col[base + r] = (int)(p & 0x3FFFFu);
  }
}

// ---- shared helpers for the fused agg+GEMM kernels ----
static __device__ __forceinline__ void stage_w(const float* __restrict__ W,
                                               unsigned short* __restrict__ T,
                                               int n, int oct){
  unsigned int pk[4];
  #pragma unroll
  for (int i = 0; i < 4; i++){
    float lo = W[(oct * 8 + 2 * i)     * 64 + n];
    float hi = W[(oct * 8 + 2 * i + 1) * 64 + n];
    pk[i] = ((unsigned int)f2b(hi) << 16) | f2b(lo);
  }
  *(uint4*)(T + SWZ(n, oct)) = *(uint4*)pk;
}

static __device__ __forceinline__ void gather_mean(
    const unsigned short* __restrict__ X, const int* __restrict__ col,
    int rbeg, int rend, int g, int fl, f32x2v acc[4]){
  int cid = 0;
  int deg = rend - rbeg;
  if (fl < deg) cid = col[rbeg + fl];
  for (int p = rbeg; p < rend; p += 8){
    int nb = rend - p; if (nb > 8) nb = 8;
    int cc = cid;
    int rem = rend - (p + 8);
    if (rem > 0 && fl < rem) cid = col[p + 8 + fl];
    #pragma unroll
    for (int k = 0; k < 8; ++k){
      int c = __shfl(cc, (g << 3) + k, 64);
      if (k < nb){
        uint4 d = *(const uint4*)(X + (long long)c * F + fl * 8);
        acc[0] = pk_add(acc[0], unp(d.x));
        acc[1] = pk_add(acc[1], unp(d.y));
        acc[2] = pk_add(acc[2], unp(d.z));
        acc[3] = pk_add(acc[3], unp(d.w));
      }
    }
  }
}

static __device__ __forceinline__ uint4 mean_pack(f32x2v acc[4], int deg){
  float r = deg ? (1.0f / (float)deg) : 0.f;
  uint4 o;
  o.x = ((unsigned int)f2b(acc[0].y * r) << 16) | f2b(acc[0].x * r);
  o.y = ((unsigned int)f2b(acc[1].y * r) << 16) | f2b(acc[1].x * r);
  o.z = ((unsigned int)f2b(acc[2].y * r) << 16) | f2b(acc[2].x * r);
  o.w = ((unsigned int)f2b(acc[3].y * r) << 16) | f2b(acc[3].x * r);
  return o;
}

// ---- entity/evidence fused agg+GEMM body (uses first 3*4096 shorts of L = 24 KB) ----
static __device__ __forceinline__ void aggemm_body(int b, unsigned short* L,
    const unsigned short* __restrict__ Xg,
    const unsigned short* __restrict__ Xe, const unsigned short* __restrict__ Xv,
    const int* __restrict__ R, const int* __restrict__ col,
    const float* __restrict__ Wl, const float* __restrict__ Wr,
    const float* __restrict__ bl,
    unsigned short* __restrict__ He, unsigned short* __restrict__ Hv)
{
  unsigned short* WTm = L;
  unsigned short* WTr = L + 4096;
  unsigned short* MT  = L + 2 * 4096;
  int seg, m0, Rb, Ms;
  const unsigned short* Xroot;
  unsigned short* Hout;
  if (b < NEB){ seg = 0; m0 = b * 64;         Rb = 2*N_CLAIM;            Ms = N_ENTITY;   Xroot = Xe; Hout = He; }
  else        { seg = 1; m0 = (b - NEB) * 64; Rb = 2*N_CLAIM + N_ENTITY; Ms = N_EVIDENCE; Xroot = Xv; Hout = Hv; }
  int tid = threadIdx.x;
  int sn = tid & 63, soct = tid >> 6;
  stage_w(Wl + (size_t)(2 + seg) * 4096, WTm, sn, soct);
  stage_w(Wr + (size_t)(2 + seg) * 4096, WTr, sn, soct);
  int lane = tid & 63;
  int wv   = tid >> 6;
  int g    = lane >> 3;
  int fl   = lane & 7;
  int rowl = wv * 8 + g;
  int rowg = m0 + rowl;
  bool act = rowg < Ms;
  int rbeg = 0, rend = 0;
  if (act){ rbeg = R[Rb + rowg]; rend = R[Rb + rowg + 1]; }
  f32x2v z = {0.f, 0.f};
  f32x2v acc[4] = {z, z, z, z};
  gather_mean(Xg, col, rbeg, rend, g, fl, acc);
  *(uint4*)(MT + SWZ(rowl, fl)) = mean_pack(acc, rend - rbeg);
  __syncthreads();
  int rt = wv >> 1;
  int c0 = (wv & 1) * 2;
  int quad = lane >> 4, l16 = lane & 15;
  int arow = m0 + rt * 16 + l16; if (arow >= Ms) arow = Ms - 1;
  f32x4 zz = {0.f, 0.f, 0.f, 0.f};
  f32x4 gacc[2] = {zz, zz};
  #pragma unroll
  for (int kk = 0; kk < 64; kk += 32){
    int ch = (kk >> 3) + quad;
    bf16x8 am = *(const bf16x8*)(MT + SWZ(rt * 16 + l16, ch));
    bf16x8 ar = *(const bf16x8*)(Xroot + (long long)arow * F + kk + quad * 8);
    #pragma unroll
    for (int c = 0; c < 2; c++){
      int bn = (c0 + c) * 16 + l16;
      bf16x8 bm = *(const bf16x8*)(WTm + SWZ(bn, ch));
      bf16x8 br = *(const bf16x8*)(WTr + SWZ(bn, ch));
      gacc[c] = __builtin_amdgcn_mfma_f32_16x16x32_bf16(am, bm, gacc[c], 0, 0, 0);
      gacc[c] = __builtin_amdgcn_mfma_f32_16x16x32_bf16(ar, br, gacc[c], 0, 0, 0);
    }
  }
  const float* blp = bl + (size_t)(2 + seg) * 64;
  #pragma unroll
  for (int c = 0; c < 2; c++){
    int n = (c0 + c) * 16 + l16;
    float bv = blp[n];
    #pragma unroll
    for (int r4 = 0; r4 < 4; r4++){
      int row = m0 + rt * 16 + quad * 4 + r4;
      if (row < Ms){
        float v2 = gacc[c][r4] + bv;
        Hout[(long long)row * F + n] = f2b(fmaxf(v2, 0.f));
      }
    }
  }
}

// ---- claims fused agg+GEMM body: 4 weight tiles + ONE mean tile (40 KB) ----
static __device__ __forceinline__ void cagg_body(int bid, unsigned short* L,
    const unsigned short* __restrict__ Xg0, const unsigned short* __restrict__ Xg1,
    const unsigned short* __restrict__ Xr,
    const int* __restrict__ R, const int* __restrict__ col,
    const int* __restrict__ list, const int* __restrict__ nu_ptr,
    const float* __restrict__ W0, const float* __restrict__ W1,
    const float* __restrict__ W2, const float* __restrict__ W3,
    const float* __restrict__ b0, const float* __restrict__ b1,
    unsigned short* __restrict__ Hout, int rootlist, int relu,
    const float* __restrict__ Wc, float* __restrict__ logits)
{
  int M = *nu_ptr;
  if (bid * 64 >= M) return;
  unsigned short* WT = L;               // 4 x 8 KB weight tiles
  unsigned short* MT = L + 4 * 4096;    // 8 KB mean tile (reused seg0 -> seg1)
  int tid = threadIdx.x;
  int sn = tid & 63, soct = tid >> 6;
  stage_w(W0, WT,            sn, soct);
  stage_w(W1, WT + 4096,     sn, soct);
  stage_w(W2, WT + 2 * 4096, sn, soct);
  stage_w(W3, WT + 3 * 4096, sn, soct);
  int m0 = bid * 64;
  int lane = tid & 63;
  int wv   = tid >> 6;
  int g    = lane >> 3;
  int fl   = lane & 7;
  int rowl = wv * 8 + g;
  int rowg = m0 + rowl;
  bool act = rowg < M;
  int node0 = act ? list[rowg] : 0;
  // ---- seg0 gather ----
  {
    int rbeg = 0, rend = 0;
    if (act){ rbeg = R[node0]; rend = R[node0 + 1]; }
    f32x2v z = {0.f, 0.f};
    f32x2v acc[4] = {z, z, z, z};
    gather_mean(Xg0, col, rbeg, rend, g, fl, acc);
    *(uint4*)(MT + SWZ(rowl, fl)) = mean_pack(acc, rend - rbeg);
  }
  __syncthreads();
  // ---- GEMM pass A: mean0@W0 + root@W2 + root@W3 ----
  int rt = wv >> 1;
  int c0 = (wv & 1) * 2;
  int quad = lane >> 4, l16 = lane & 15;
  int arow = m0 + rt * 16 + l16; if (arow >= M) arow = M - 1;
  long long rrow = rootlist ? list[arow] : arow;
  f32x4 zz = {0.f, 0.f, 0.f, 0.f};
  f32x4 gacc[2] = {zz, zz};
  #pragma unroll
  for (int kk = 0; kk < 64; kk += 32){
    int ch = (kk >> 3) + quad;
    bf16x8 a0 = *(const bf16x8*)(MT + SWZ(rt * 16 + l16, ch));
    bf16x8 ar = *(const bf16x8*)(Xr + rrow * F + kk + quad * 8);
    #pragma unroll
    for (int c = 0; c < 2; c++){
      int bn = (c0 + c) * 16 + l16;
      bf16x8 w0 = *(const bf16x8*)(WT +            SWZ(bn, ch));
      bf16x8 w2 = *(const bf16x8*)(WT + 2 * 4096 + SWZ(bn, ch));
      bf16x8 w3 = *(const bf16x8*)(WT + 3 * 4096 + SWZ(bn, ch));
      gacc[c] = __builtin_amdgcn_mfma_f32_16x16x32_bf16(a0, w0, gacc[c], 0, 0, 0);
      gacc[c] = __builtin_amdgcn_mfma_f32_16x16x32_bf16(ar, w2, gacc[c], 0, 0, 0);
      gacc[c] = __builtin_amdgcn_mfma_f32_16x16x32_bf16(ar, w3, gacc[c], 0, 0, 0);
    }
  }
  __syncthreads();   // all waves done reading MT (seg0)
  // ---- seg1 gather (overwrites MT) ----
  {
    int n1 = node0 + N_CLAIM;
    int rbeg = 0, rend = 0;
    if (act){ rbeg = R[n1]; rend = R[n1 + 1]; }
    f32x2v z = {0.f, 0.f};
    f32x2v acc[4] = {z, z, z, z};
    gather_mean(Xg1, col, rbeg, rend, g, fl, acc);
    *(uint4*)(MT + SWZ(rowl, fl)) = mean_pack(acc, rend - rbeg);
  }
  __syncthreads();
  // ---- GEMM pass B: mean1@W1 ----
  #pragma unroll
  for (int kk = 0; kk < 64; kk += 32){
    int ch = (kk >> 3) + quad;
    bf16x8 a1 = *(const bf16x8*)(MT + SWZ(rt * 16 + l16, ch));
    #pragma unroll
    for (int c = 0; c < 2; c++){
      int bn = (c0 + c) * 16 + l16;
      bf16x8 w1 = *(const bf16x8*)(WT + 4096 + SWZ(bn, ch));
      gacc[c] = __builtin_amdgcn_mfma_f32_16x16x32_bf16(a1, w1, gacc[c], 0, 0, 0);
    }
  }
  if (!logits){
    // ---- store hidden (layer 1) ----
    #pragma unroll
    for (int c = 0; c < 2; c++){
      int n = (c0 + c) * 16 + l16;
      float bv = b0[n] + b1[n];
      #pragma unroll
      for (int r4 = 0; r4 < 4; r4++){
        int row = m0 + rt * 16 + quad * 4 + r4;
        if (row < M){
          float v2 = gacc[c][r4] + bv;
          if (relu) v2 = fmaxf(v2, 0.f);
          Hout[(long long)row * F + n] = f2b(v2);
        }
      }
    }
  } else {
    // ---- fused classifier: logits[row] = (h2row) @ Wc (bias bc added in k_out2) ----
    __syncthreads();                    // done reading MT; reuse as partial buffer
    float* P = (float*)MT;              // P[row64][half][j] : 64*2*2 floats = 1 KB
    #pragma unroll
    for (int r4 = 0; r4 < 4; r4++){
      float p0 = 0.f, p1 = 0.f;
      #pragma unroll
      for (int c = 0; c < 2; c++){
        int n = (c0 + c) * 16 + l16;
        float v2 = gacc[c][r4] + b0[n] + b1[n];
        p0 += v2 * Wc[n * 2];
        p1 += v2 * Wc[n * 2 + 1];
      }
      #pragma unroll
      for (int off = 8; off; off >>= 1){
        p0 += __shfl_xor(p0, off, 64);
        p1 += __shfl_xor(p1, off, 64);
      }
      if (l16 == 0){
        int row = rt * 16 + quad * 4 + r4;
        P[row * 4 + (wv & 1) * 2]     = p0;
        P[row * 4 + (wv & 1) * 2 + 1] = p1;
      }
    }
    __syncthreads();
    if (tid < 128){
      int row = tid >> 1, j = tid & 1;
      if (m0 + row < M)
        logits[(long long)(m0 + row) * 2 + j] = P[row * 4 + j] + P[row * 4 + 2 + j];
    }
  }
}

// ---------------- layer-1 mega-kernel: claims cagg | ent/evid aggemm ----------------
__global__ __launch_bounds__(512) void k_l1(
    const int* __restrict__ R, const int* __restrict__ col,
    const unsigned short* __restrict__ xb_c, const unsigned short* __restrict__ xb_e,
    const unsigned short* __restrict__ xb_v,
    const int* __restrict__ list, const int* __restrict__ nu,
    const float* __restrict__ Wl1, const float* __restrict__ Wr1,
    const float* __restrict__ bl1,
    unsigned short* __restrict__ h1c, unsigned short* __restrict__ h1e,
    unsigned short* __restrict__ h1v)
{
  __shared__ __align__(16) unsigned short L[5 * 4096];   // 40 KB -> 4 blocks/CU
  int bid = blockIdx.x;
  if (bid < NCB){
    cagg_body(bid, L, xb_e, xb_v, xb_c, R, col, list, nu,
              Wl1, Wl1 + 4096, Wr1, Wr1 + 4096, bl1, bl1 + 64, h1c, 1, 1,
              nullptr, nullptr);
  } else {
    aggemm_body(bid - NCB, L, xb_c, xb_e, xb_v, R, col, Wl1, Wr1, bl1, h1e, h1v);
  }
}

// ---------------- layer-2 claims kernel + fused classifier ----------------
__global__ __launch_bounds__(512) void k_cagg2(
    const unsigned short* __restrict__ h1e, const unsigned short* __restrict__ h1v,
    const unsigned short* __restrict__ h1c,
    const int* __restrict__ R, const int* __restrict__ col,
    const int* __restrict__ list, const int* __restrict__ nu,
    const float* __restrict__ Wl2, const float* __restrict__ Wr2,
    const float* __restrict__ bl2,
    const float* __restrict__ Wc, float* __restrict__ logits)
{
  __shared__ __align__(16) unsigned short L[5 * 4096];   // 40 KB
  cagg_body(blockIdx.x, L, h1e, h1v, h1c, R, col, list, nu,
            Wl2, Wl2 + 4096, Wr2, Wr2 + 4096, bl2, bl2 + 64, nullptr, 0, 0,
            Wc, logits);
}

// ---------------- final: per-batch logit gather + bias ----------------
__global__ void k_out2(const float* __restrict__ logits,
                       const int* __restrict__ cbi,
                       const int* __restrict__ rank,
                       const float* __restrict__ bcp,
                       float* __restrict__ out){
  int w = blockIdx.x * blockDim.x + threadIdx.x;
  if (w >= BATCH) return;
  int rk = rank[cbi[w]];
  float2 l = ((const float2*)logits)[rk];
  out[2 * w]     = l.x + bcp[0];
  out[2 * w + 1] = l.y + bcp[1];
}

extern "C" void kernel_launch(void* const* d_in, const int* in_sizes, int n_in,
                              void* d_out, int out_size, void* d_ws, size_t ws_size,
                              hipStream_t stream)
{
  const float* x_c = (const float*)d_in[0];
  const float* x_e = (const float*)d_in[1];
  const float* x_v = (const float*)d_in[2];
  const int*   ei  = (const int*)d_in[3];
  const int*   cbi = (const int*)d_in[4];
  const float* Wl1 = (const float*)d_in[5];
  const float* bl1 = (const float*)d_in[6];
  const float* Wr1 = (const float*)d_in[7];
  const float* Wl2 = (const float*)d_in[8];
  const float* bl2 = (const float*)d_in[9];
  const float* Wr2 = (const float*)d_in[10];
  const float* Wc  = (const float*)d_in[11];
  const float* bc  = (const float*)d_in[12];
  float* out = (float*)d_out;

  char* ws = (char*)d_ws;
  size_t off = 0;
  auto alloc = [&](size_t bytes) -> char* {
    char* p = ws + off;
    off += (bytes + 255) & ~(size_t)255;
    return p;
  };
  int* R       = (int*)alloc((size_t)(NT + 1) * 4);
  int* cursor  = (int*)alloc((size_t)NBKT * 4);
  unsigned int* bits = (unsigned int*)alloc((size_t)NBITS_W * 4);
  int* rank    = (int*)alloc((size_t)N_CLAIM * 4);
  int* list    = (int*)alloc((size_t)BATCH * 4);
  int* nu      = (int*)alloc(256);
  int* col     = (int*)alloc((size_t)4 * NEDGE * 4);
  unsigned int* pairs = (unsigned int*)alloc((size_t)NBKT * CAP * 4);   // dead after k_csr
  unsigned short* xb_c  = (unsigned short*)alloc((size_t)N_CLAIM    * F * 2);
  unsigned short* xb_e  = (unsigned short*)alloc((size_t)N_ENTITY   * F * 2);
  unsigned short* xb_v  = (unsigned short*)alloc((size_t)N_EVIDENCE * F * 2);
  unsigned short* h1c   = (unsigned short*)alloc((size_t)BATCH * F * 2);   // compacted
  unsigned short* h1e   = (unsigned short*)alloc((size_t)N_ENTITY   * F * 2);
  unsigned short* h1v   = (unsigned short*)alloc((size_t)N_EVIDENCE * F * 2);
  float* logits = (float*)pairs;   // alias dead pairs region; [BATCH][2] fp32

  hipMemsetAsync(bits, 0, (size_t)NBITS_W * 4, stream);
  hipMemsetAsync(nu, 0, 4, stream);

  k_mark<<<(BATCH + 255) / 256, 256, 0, stream>>>(cbi, bits, cursor);

  k_front<<<FRONTB, 256, 0, stream>>>(ei, bits, cursor, pairs,
      x_c, x_e, x_v, xb_c, xb_e, xb_v, rank, list, nu);

  k_csr<<<NBKT, 1024, 0, stream>>>(pairs, cursor, R, col);

  k_l1<<<L1B, 512, 0, stream>>>(R, col, xb_c, xb_e, xb_v, list, nu,
      Wl1, Wr1, bl1, h1c, h1e, h1v);

  k_cagg2<<<NCB, 512, 0, stream>>>(h1e, h1v, h1c, R, col, list, nu,
      Wl2, Wr2, bl2, Wc, logits);

  k_out2<<<(BATCH + 255) / 256, 256, 0, stream>>>(logits, cbi, rank, bc, out);
}